// Round 5
// baseline (10209.843 us; speedup 1.0000x reference)
//
#include <hip/hip_runtime.h>
#include <hip/hip_bf16.h>
#include <stdint.h>

#define LATENT 256
#define HIDDEN 1024
#define GOUT 512
#define NB 32
#define TT 512
#define G3 1536

typedef float f32x4 __attribute__((ext_vector_type(4)));
typedef short s16x8 __attribute__((ext_vector_type(8)));
typedef uint32_t u32;
typedef unsigned long long u64;

#define GLP(p) ((const __attribute__((address_space(1))) u32*)(p))
#define LLP(p) ((__attribute__((address_space(3))) u32*)(p))

__device__ __forceinline__ short f2bf(float f) {
  u32 u = __builtin_bit_cast(u32, f);
  u32 r = (u + 0x7FFFu + ((u >> 16) & 1u)) >> 16;
  return (short)r;
}
__device__ __forceinline__ float bf2f(short s) {
  u32 u = ((u32)(unsigned short)s) << 16;
  return __builtin_bit_cast(float, u);
}
__device__ __forceinline__ u32 pk2(float a, float b) {
  return (u32)(unsigned short)f2bf(a) | ((u32)(unsigned short)f2bf(b) << 16);
}
__device__ __forceinline__ s16x8 f2bf8(float4 a, float4 b) {
  s16x8 r;
  r[0] = f2bf(a.x); r[1] = f2bf(a.y); r[2] = f2bf(a.z); r[3] = f2bf(a.w);
  r[4] = f2bf(b.x); r[5] = f2bf(b.y); r[6] = f2bf(b.z); r[7] = f2bf(b.w);
  return r;
}
__device__ __forceinline__ float ldgx(const float* p) { return *p; }
__device__ __forceinline__ float ldgx(const short* p) { return bf2f(*p); }
__device__ __forceinline__ u64 ald(const u64* p) {
  return __hip_atomic_load(p, __ATOMIC_RELAXED, __HIP_MEMORY_SCOPE_AGENT);
}

// ---------------- fc + relu ----------------
__global__ __launch_bounds__(256) void fc_kernel(const float* __restrict__ z,
                                                 const float* __restrict__ fc_w,
                                                 const float* __restrict__ fc_b,
                                                 float* __restrict__ hfc) {
  __shared__ float zs[LATENT];
  int tid = threadIdx.x;
  int gid = blockIdx.x * 256 + tid;
  int b = gid >> 10, j = gid & 1023;
  zs[tid] = z[b * LATENT + tid];
  __syncthreads();
  const float4* wr = (const float4*)(fc_w + (size_t)j * LATENT);
  float s = 0.f;
#pragma unroll
  for (int k = 0; k < LATENT / 4; ++k) {
    float4 wv = wr[k];
    float4 zv = *(const float4*)&zs[k * 4];
    s += wv.x * zv.x + wv.y * zv.y + wv.z * zv.z + wv.w * zv.w;
  }
  s += fc_b[j];
  hfc[gid] = fmaxf(s, 0.f);
}

// ------------- x0[t][b][k] = bf16(hfc[b][k] + chord[b][t][k]/100) -------------
__global__ __launch_bounds__(256) void x0_kernel(const float* __restrict__ hfc,
                                                 const float* __restrict__ chord,
                                                 short* __restrict__ x0) {
  int r = blockIdx.x;          // r = t*32 + b
  int b = r & 31, t = r >> 5;
  int k = threadIdx.x * 4;
  float4 c = *(const float4*)(chord + ((size_t)b * TT + t) * HIDDEN + k);
  float4 h = *(const float4*)(hfc + (size_t)b * HIDDEN + k);
  u32 p0 = pk2(h.x + c.x * 0.01f, h.y + c.y * 0.01f);
  u32 p1 = pk2(h.z + c.z * 0.01f, h.w + c.w * 0.01f);
  uint2 pv; pv.x = p0; pv.y = p1;
  *(uint2*)(x0 + (size_t)r * HIDDEN + k) = pv;
}

// ---------------- fp32 -> bf16 weight convert ----------------
__global__ __launch_bounds__(256) void cvt_kernel(const float* __restrict__ src,
                                                  short* __restrict__ dst, int n4) {
  int i = blockIdx.x * 256 + threadIdx.x;
  if (i < n4) {
    float4 v = ((const float4*)src)[i];
    uint2 pv; pv.x = pk2(v.x, v.y); pv.y = pk2(v.z, v.w);
    ((uint2*)dst)[i] = pv;
  }
}

// ---------------- GEMM: C[M][N] = A[M][K](bf16) @ Bw[N][K]^T(bf16) ----------------
template <typename OutT>
__global__ __launch_bounds__(256) void gemm_bt(const short* __restrict__ A,
                                               const short* __restrict__ Bw,
                                               OutT* __restrict__ C, int M, int N, int K) {
  __shared__ short As[128 * 32];
  __shared__ short Bs[128 * 32];
  const int tid = threadIdx.x;
  const int lane = tid & 63, wave = tid >> 6;
  const int l15 = lane & 15, quad = lane >> 4;
  const int n0 = blockIdx.x * 128, m0 = blockIdx.y * 128;
  const int wm = (wave >> 1) * 64, wn = (wave & 1) * 64;
  f32x4 acc[4][4] = {};
  for (int k0 = 0; k0 < K; k0 += 32) {
#pragma unroll
    for (int c = 0; c < 2; ++c) {
      int idx = c * 256 + tid;
      int row = idx >> 2, cs = (idx & 3) * 8;
      const u32* ga = (const u32*)(A + (size_t)(m0 + row) * K + k0 + cs);
      const u32* gb = (const u32*)(Bw + (size_t)(n0 + row) * K + k0 + cs);
      u32* sa = (u32*)As + (size_t)(c * 256 + wave * 64) * 4;
      u32* sb = (u32*)Bs + (size_t)(c * 256 + wave * 64) * 4;
      __builtin_amdgcn_global_load_lds(GLP(ga), LLP(sa), 16, 0, 0);
      __builtin_amdgcn_global_load_lds(GLP(gb), LLP(sb), 16, 0, 0);
    }
    __syncthreads();
    s16x8 af[4], bfr[4];
#pragma unroll
    for (int i = 0; i < 4; ++i)
      af[i] = *(const s16x8*)(As + (wm + i * 16 + l15) * 32 + quad * 8);
#pragma unroll
    for (int j = 0; j < 4; ++j)
      bfr[j] = *(const s16x8*)(Bs + (wn + j * 16 + l15) * 32 + quad * 8);
#pragma unroll
    for (int i = 0; i < 4; ++i)
#pragma unroll
      for (int j = 0; j < 4; ++j)
        acc[i][j] = __builtin_amdgcn_mfma_f32_16x16x32_bf16(af[i], bfr[j], acc[i][j], 0, 0, 0);
    __syncthreads();
  }
#pragma unroll
  for (int i = 0; i < 4; ++i)
#pragma unroll
    for (int j = 0; j < 4; ++j)
#pragma unroll
      for (int r = 0; r < 4; ++r) {
        int m = m0 + wm + i * 16 + quad * 4 + r;
        int n = n0 + wn + j * 16 + l15;
        float v = acc[i][j][r];
        if constexpr (__is_same(OutT, float)) C[(size_t)m * N + n] = v;
        else C[(size_t)m * N + n] = f2bf(v);
      }
}

// ================= GRU layer v7: v6 + vmcnt-clean critical path ==============
// Post-mortem v6: vmcnt retires VMEM in ISSUE ORDER. v6 issued h-stores, 12 gx
// HBM loads (~900cy) and output stores BEFORE the next step's poll loads, so
// consuming the first poll value required ALL of them complete -> ~900cy of
// HBM latency inside the poll-detect path every step. Fix:
//   - gx prefetch double-buffered (pgxA/pgxB, static copy at loop end) and
//     issued right AFTER the barrier: consumed (copy) before next poll issue,
//     covered by the MFMA+combine+stores window.
//   - 4 WGs x 8 waves per group (was 8x4): poll words/thread 16->8 (group poll
//     volume = v3's proven 128KB/round), and 2 waves/SIMD for latency overlap.
// Everything else identical to the twice-passed v6 protocol: thread-linear
// coalesced polls staged to swizzled LDS, in-register 3-gate combine via MFMA
// C-layout (col=unit=l15, row=batch=quad*4+r), tagged u64 depth-2 ring
// (tag hi32 = tb+t+1, payload 2 bf16, relaxed agent atomics), per-layer tag
// base + clr each launch, XCD pinning bid&7 in {0,4}.
__global__ __launch_bounds__(256) void clr_kernel(u64* __restrict__ p) {
  p[(size_t)blockIdx.x * 256 + threadIdx.x] = 0ull;
}

template <typename GxT>
__global__ __launch_bounds__(512, 2) void gru_seq(const GxT* __restrict__ gx,      // [T][32][1536]
                                                  const float* __restrict__ w_hh,  // [1536][512]
                                                  const float* __restrict__ b_ih,
                                                  const float* __restrict__ b_hh,
                                                  u64* __restrict__ h_buf,         // [2 grp][2 slot][16 b][256 w]
                                                  int tb,
                                                  short* __restrict__ x_out,       // [T][32][512] bf16 or null
                                                  float* __restrict__ f_out,       // [32][T][512] fp32 or null
                                                  const int* __restrict__ seq_lens) {
  const int bid = blockIdx.x;                 // grid 32
  const int xs = bid & 7;
  int g;
  if (xs == 0) g = 0;
  else if (xs == 4) g = 1;
  else return;                                // dummy WG (XCD-pinning pad)
  const int wg = bid >> 3;                    // 0..3: unit-block of 128
  const int tid = threadIdx.x;                // 0..511
  const int lane = tid & 63, wave = tid >> 6; // 8 waves
  const int l15 = lane & 15, quad = lane >> 4;
  const int u = wg * 128 + wave * 16 + l15;   // owned unit

  __shared__ u32 h_lds[2][16 * 256];          // 32 KB double-buffered h tile

  u64* hb = h_buf + (size_t)g * 8192;

  // --- persistent w_hh fragments: 3 gates x 16 kb (192 VGPR) ---
  s16x8 wf[48];
#pragma unroll
  for (int kb = 0; kb < 16; ++kb)
#pragma unroll
    for (int gt = 0; gt < 3; ++gt) {
      const float* p = w_hh + (size_t)(gt * 512 + u) * 512 + kb * 32 + quad * 8;
      wf[gt * 16 + kb] = f2bf8(*(const float4*)p, *(const float4*)(p + 4));
    }

  const float bihr = b_ih[u], bihz = b_ih[512 + u], bihn = b_ih[1024 + u];
  const float bhhr = b_hh[u], bhhz = b_hh[512 + u], bhhn = b_hh[1024 + u];

  float hprev[4] = {0.f, 0.f, 0.f, 0.f};
  int slen[4] = {0, 0, 0, 0};
  float pgxA[3][4], pgxB[3][4];
#pragma unroll
  for (int r = 0; r < 4; ++r) {
    const int gb = g * 16 + quad * 4 + r;
    if (f_out) slen[r] = seq_lens[gb];
#pragma unroll
    for (int gt = 0; gt < 3; ++gt) {
      pgxA[gt][r] = ldgx(&gx[(size_t)gb * G3 + gt * 512 + u]);   // t=0
      pgxB[gt][r] = 0.f;
    }
  }

  // poll mapping: thread owns col tid&255, rows rowbase..rowbase+7
  const int colt = tid & 255;
  const int rowbase = (tid >> 8) * 8;

  for (int t = 0; t < TT; ++t) {
    // ---- coalesced poll of h(t-1) + swizzled LDS stage ----
    if (t > 0) {
      const u64* base = hb + ((t - 1) & 1) * 4096 + rowbase * 256 + colt;
      const u32 want = (u32)(tb + t);
      u32* dl = h_lds[t & 1];
      u64 v[8];
#pragma unroll
      for (int j = 0; j < 8; ++j) v[j] = ald(base + j * 256);
#pragma unroll
      for (int j = 0; j < 8; ++j) {
        while ((u32)(v[j] >> 32) != want) v[j] = ald(base + j * 256);
        const int row = rowbase + j;                        // row&7 == j
        dl[row * 256 + (colt ^ (j << 2) ^ ((j & 1) << 4))] = (u32)v[j];
      }
    }
    __syncthreads();

    // ---- gx prefetch for t+1, issued right after the barrier (vmcnt-clean:
    //      consumed by the pgxA copy BEFORE next step's polls are issued) ----
    if (t + 1 < TT) {
#pragma unroll
      for (int gt = 0; gt < 3; ++gt)
#pragma unroll
        for (int r = 0; r < 4; ++r) {
          const int gb = g * 16 + quad * 4 + r;
          pgxB[gt][r] = ldgx(&gx[(size_t)((t + 1) * NB + gb) * G3 + gt * 512 + u]);
        }
    }

    // ---- gate MFMAs from LDS (3 round-robin acc chains) ----
    f32x4 ar = {0.f, 0.f, 0.f, 0.f}, az = ar, an = ar;
    if (t > 0) {
      const u32* hl = h_lds[t & 1];
      const int rbase = l15 * 256;
      const int rx = ((l15 & 7) << 2) ^ ((l15 & 1) << 4);
#pragma unroll
      for (int i = 0; i < 16; ++i) {
        const s16x8 fr = *(const s16x8*)&hl[rbase + ((quad * 4 + i * 16) ^ rx)];
        ar = __builtin_amdgcn_mfma_f32_16x16x32_bf16(fr, wf[i],      ar, 0, 0, 0);
        az = __builtin_amdgcn_mfma_f32_16x16x32_bf16(fr, wf[16 + i], az, 0, 0, 0);
        an = __builtin_amdgcn_mfma_f32_16x16x32_bf16(fr, wf[32 + i], an, 0, 0, 0);
      }
    }

    // ---- in-register combine + tagged h store (earliest visibility) ----
    u64* dst = hb + (t & 1) * 4096;
    const u64 tg = ((u64)(u32)(tb + t + 1)) << 32;
#pragma unroll
    for (int r = 0; r < 4; ++r) {
      const float xr = pgxA[0][r] + bihr + ar[r] + bhhr;
      const float xz = pgxA[1][r] + bihz + az[r] + bhhz;
      const float rr = 1.f / (1.f + __expf(-xr));
      const float zz = 1.f / (1.f + __expf(-xz));
      const float pre = pgxA[2][r] + bihn + rr * (an[r] + bhhn);
      const float ax = fabsf(pre);
      const float e = __expf(-2.f * ax);
      const float nn = copysignf((1.f - e) / (1.f + e), pre);
      const float h = (1.f - zz) * nn + zz * hprev[r];
      hprev[r] = h;
      const float other = __shfl_xor(h, 1);
      if (!(lane & 1))
        __hip_atomic_store(dst + (quad * 4 + r) * 256 + (u >> 1), (u64)pk2(h, other) | tg,
                           __ATOMIC_RELAXED, __HIP_MEMORY_SCOPE_AGENT);
    }
    // ---- output stores (off the critical path) ----
#pragma unroll
    for (int r = 0; r < 4; ++r) {
      const int gb = g * 16 + quad * 4 + r;
      if (x_out) x_out[(size_t)(t * NB + gb) * 512 + u] = f2bf(hprev[r]);
      if (f_out) f_out[((size_t)gb * TT + t) * 512 + u] = (t < slen[r]) ? hprev[r] : 0.f;
    }
    // ---- consume prefetch (waits the gx loads here, NOT in the poll path) ----
#pragma unroll
    for (int gt = 0; gt < 3; ++gt)
#pragma unroll
      for (int r = 0; r < 4; ++r) pgxA[gt][r] = pgxB[gt][r];
  }
}

extern "C" void kernel_launch(void* const* d_in, const int* in_sizes, int n_in,
                              void* d_out, int out_size, void* d_ws, size_t ws_size,
                              hipStream_t stream) {
  (void)in_sizes; (void)n_in; (void)out_size;
  const float* z       = (const float*)d_in[0];
  const int*   seq     = (const int*)d_in[1];
  const float* chord   = (const float*)d_in[2];
  const float* fc_w    = (const float*)d_in[3];
  const float* fc_b    = (const float*)d_in[4];
  const float* w_ih[3] = {(const float*)d_in[5], (const float*)d_in[9],  (const float*)d_in[13]};
  const float* w_hh[3] = {(const float*)d_in[6], (const float*)d_in[10], (const float*)d_in[14]};
  const float* b_ih[3] = {(const float*)d_in[7], (const float*)d_in[11], (const float*)d_in[15]};
  const float* b_hh[3] = {(const float*)d_in[8], (const float*)d_in[12], (const float*)d_in[16]};

  char* w = (char*)d_ws;
  size_t off = 0;
  auto alloc = [&](size_t bytes) -> void* {
    void* p = w + off;
    off = (off + bytes + 255) & ~(size_t)255;
    return p;
  };
  u64*   hbuf = (u64*)alloc((size_t)2 * 8192 * 8);           // tagged h rings (128 KB)
  float* hfc  = (float*)alloc((size_t)NB * HIDDEN * 4);
  short* x0   = (short*)alloc((size_t)TT * NB * HIDDEN * 2);
  short* x1   = (short*)alloc((size_t)TT * NB * GOUT * 2);   // reused as x2
  short* w0b  = (short*)alloc((size_t)G3 * HIDDEN * 2);
  short* w1b  = (short*)alloc((size_t)G3 * GOUT * 2);
  short* w2b  = (short*)alloc((size_t)G3 * GOUT * 2);
  size_t fixed = off;
  bool gx_f32 = (fixed + (size_t)TT * NB * G3 * 4) <= ws_size;
  void* gx = alloc(gx_f32 ? (size_t)TT * NB * G3 * 4 : (size_t)TT * NB * G3 * 2);

  clr_kernel<<<64, 256, 0, stream>>>(hbuf);
  fc_kernel<<<128, 256, 0, stream>>>(z, fc_w, fc_b, hfc);
  x0_kernel<<<TT * NB, 256, 0, stream>>>(hfc, chord, x0);
  cvt_kernel<<<(G3 * HIDDEN / 4 + 255) / 256, 256, 0, stream>>>(w_ih[0], w0b, G3 * HIDDEN / 4);
  cvt_kernel<<<(G3 * GOUT / 4 + 255) / 256, 256, 0, stream>>>(w_ih[1], w1b, G3 * GOUT / 4);
  cvt_kernel<<<(G3 * GOUT / 4 + 255) / 256, 256, 0, stream>>>(w_ih[2], w2b, G3 * GOUT / 4);

  dim3 gg(G3 / 128, TT * NB / 128);
  if (gx_f32) {
    float* gxf = (float*)gx;
    gemm_bt<float><<<gg, 256, 0, stream>>>(x0, w0b, gxf, TT * NB, G3, HIDDEN);
    gru_seq<float><<<32, 512, 0, stream>>>(gxf, w_hh[0], b_ih[0], b_hh[0], hbuf, 0 * 1024, x1, nullptr, seq);
    gemm_bt<float><<<gg, 256, 0, stream>>>(x1, w1b, gxf, TT * NB, G3, GOUT);
    gru_seq<float><<<32, 512, 0, stream>>>(gxf, w_hh[1], b_ih[1], b_hh[1], hbuf, 1 * 1024, x1, nullptr, seq);
    gemm_bt<float><<<gg, 256, 0, stream>>>(x1, w2b, gxf, TT * NB, G3, GOUT);
    gru_seq<float><<<32, 512, 0, stream>>>(gxf, w_hh[2], b_ih[2], b_hh[2], hbuf, 2 * 1024, nullptr, (float*)d_out, seq);
  } else {
    short* gxb = (short*)gx;
    gemm_bt<short><<<gg, 256, 0, stream>>>(x0, w0b, gxb, TT * NB, G3, HIDDEN);
    gru_seq<short><<<32, 512, 0, stream>>>(gxb, w_hh[0], b_ih[0], b_hh[0], hbuf, 0 * 1024, x1, nullptr, seq);
    gemm_bt<short><<<gg, 256, 0, stream>>>(x1, w1b, gxb, TT * NB, G3, GOUT);
    gru_seq<short><<<32, 512, 0, stream>>>(gxb, w_hh[1], b_ih[1], b_hh[1], hbuf, 1 * 1024, x1, nullptr, seq);
    gemm_bt<short><<<gg, 256, 0, stream>>>(x1, w2b, gxb, TT * NB, G3, GOUT);
    gru_seq<short><<<32, 512, 0, stream>>>(gxb, w_hh[2], b_ih[2], b_hh[2], hbuf, 2 * 1024, nullptr, (float*)d_out, seq);
  }
}

// Round 6
// 10041.225 us; speedup vs baseline: 1.0168x; 1.0168x over previous
//
#include <hip/hip_runtime.h>
#include <hip/hip_bf16.h>
#include <stdint.h>

#define LATENT 256
#define HIDDEN 1024
#define GOUT 512
#define NB 32
#define TT 512
#define G3 1536

typedef float f32x4 __attribute__((ext_vector_type(4)));
typedef short s16x8 __attribute__((ext_vector_type(8)));
typedef uint32_t u32;
typedef unsigned long long u64;

#define GLP(p) ((const __attribute__((address_space(1))) u32*)(p))
#define LLP(p) ((__attribute__((address_space(3))) u32*)(p))

__device__ __forceinline__ short f2bf(float f) {
  u32 u = __builtin_bit_cast(u32, f);
  u32 r = (u + 0x7FFFu + ((u >> 16) & 1u)) >> 16;
  return (short)r;
}
__device__ __forceinline__ float bf2f(short s) {
  u32 u = ((u32)(unsigned short)s) << 16;
  return __builtin_bit_cast(float, u);
}
__device__ __forceinline__ u32 pk2(float a, float b) {
  return (u32)(unsigned short)f2bf(a) | ((u32)(unsigned short)f2bf(b) << 16);
}
__device__ __forceinline__ s16x8 f2bf8(float4 a, float4 b) {
  s16x8 r;
  r[0] = f2bf(a.x); r[1] = f2bf(a.y); r[2] = f2bf(a.z); r[3] = f2bf(a.w);
  r[4] = f2bf(b.x); r[5] = f2bf(b.y); r[6] = f2bf(b.z); r[7] = f2bf(b.w);
  return r;
}
__device__ __forceinline__ float ldgx(const float* p) { return *p; }
__device__ __forceinline__ float ldgx(const short* p) { return bf2f(*p); }
__device__ __forceinline__ u64 ald(const u64* p) {
  return __hip_atomic_load(p, __ATOMIC_RELAXED, __HIP_MEMORY_SCOPE_AGENT);
}

// ---------------- fc + relu ----------------
__global__ __launch_bounds__(256) void fc_kernel(const float* __restrict__ z,
                                                 const float* __restrict__ fc_w,
                                                 const float* __restrict__ fc_b,
                                                 float* __restrict__ hfc) {
  __shared__ float zs[LATENT];
  int tid = threadIdx.x;
  int gid = blockIdx.x * 256 + tid;
  int b = gid >> 10, j = gid & 1023;
  zs[tid] = z[b * LATENT + tid];
  __syncthreads();
  const float4* wr = (const float4*)(fc_w + (size_t)j * LATENT);
  float s = 0.f;
#pragma unroll
  for (int k = 0; k < LATENT / 4; ++k) {
    float4 wv = wr[k];
    float4 zv = *(const float4*)&zs[k * 4];
    s += wv.x * zv.x + wv.y * zv.y + wv.z * zv.z + wv.w * zv.w;
  }
  s += fc_b[j];
  hfc[gid] = fmaxf(s, 0.f);
}

// ------------- x0[t][b][k] = bf16(hfc[b][k] + chord[b][t][k]/100) -------------
__global__ __launch_bounds__(256) void x0_kernel(const float* __restrict__ hfc,
                                                 const float* __restrict__ chord,
                                                 short* __restrict__ x0) {
  int r = blockIdx.x;          // r = t*32 + b
  int b = r & 31, t = r >> 5;
  int k = threadIdx.x * 4;
  float4 c = *(const float4*)(chord + ((size_t)b * TT + t) * HIDDEN + k);
  float4 h = *(const float4*)(hfc + (size_t)b * HIDDEN + k);
  u32 p0 = pk2(h.x + c.x * 0.01f, h.y + c.y * 0.01f);
  u32 p1 = pk2(h.z + c.z * 0.01f, h.w + c.w * 0.01f);
  uint2 pv; pv.x = p0; pv.y = p1;
  *(uint2*)(x0 + (size_t)r * HIDDEN + k) = pv;
}

// ---------------- fp32 -> bf16 weight convert ----------------
__global__ __launch_bounds__(256) void cvt_kernel(const float* __restrict__ src,
                                                  short* __restrict__ dst, int n4) {
  int i = blockIdx.x * 256 + threadIdx.x;
  if (i < n4) {
    float4 v = ((const float4*)src)[i];
    uint2 pv; pv.x = pk2(v.x, v.y); pv.y = pk2(v.z, v.w);
    ((uint2*)dst)[i] = pv;
  }
}

// ---------------- GEMM: C[M][N] = A[M][K](bf16) @ Bw[N][K]^T(bf16) ----------------
template <typename OutT>
__global__ __launch_bounds__(256) void gemm_bt(const short* __restrict__ A,
                                               const short* __restrict__ Bw,
                                               OutT* __restrict__ C, int M, int N, int K) {
  __shared__ short As[128 * 32];
  __shared__ short Bs[128 * 32];
  const int tid = threadIdx.x;
  const int lane = tid & 63, wave = tid >> 6;
  const int l15 = lane & 15, quad = lane >> 4;
  const int n0 = blockIdx.x * 128, m0 = blockIdx.y * 128;
  const int wm = (wave >> 1) * 64, wn = (wave & 1) * 64;
  f32x4 acc[4][4] = {};
  for (int k0 = 0; k0 < K; k0 += 32) {
#pragma unroll
    for (int c = 0; c < 2; ++c) {
      int idx = c * 256 + tid;
      int row = idx >> 2, cs = (idx & 3) * 8;
      const u32* ga = (const u32*)(A + (size_t)(m0 + row) * K + k0 + cs);
      const u32* gb = (const u32*)(Bw + (size_t)(n0 + row) * K + k0 + cs);
      u32* sa = (u32*)As + (size_t)(c * 256 + wave * 64) * 4;
      u32* sb = (u32*)Bs + (size_t)(c * 256 + wave * 64) * 4;
      __builtin_amdgcn_global_load_lds(GLP(ga), LLP(sa), 16, 0, 0);
      __builtin_amdgcn_global_load_lds(GLP(gb), LLP(sb), 16, 0, 0);
    }
    __syncthreads();
    s16x8 af[4], bfr[4];
#pragma unroll
    for (int i = 0; i < 4; ++i)
      af[i] = *(const s16x8*)(As + (wm + i * 16 + l15) * 32 + quad * 8);
#pragma unroll
    for (int j = 0; j < 4; ++j)
      bfr[j] = *(const s16x8*)(Bs + (wn + j * 16 + l15) * 32 + quad * 8);
#pragma unroll
    for (int i = 0; i < 4; ++i)
#pragma unroll
      for (int j = 0; j < 4; ++j)
        acc[i][j] = __builtin_amdgcn_mfma_f32_16x16x32_bf16(af[i], bfr[j], acc[i][j], 0, 0, 0);
    __syncthreads();
  }
#pragma unroll
  for (int i = 0; i < 4; ++i)
#pragma unroll
    for (int j = 0; j < 4; ++j)
#pragma unroll
      for (int r = 0; r < 4; ++r) {
        int m = m0 + wm + i * 16 + quad * 4 + r;
        int n = n0 + wn + j * 16 + l15;
        float v = acc[i][j][r];
        if constexpr (__is_same(OutT, float)) C[(size_t)m * N + n] = v;
        else C[(size_t)m * N + n] = f2bf(v);
      }
}

// ================= GRU layer v8: batched retry + raw barrier =================
// Post-mortem v7: __launch_bounds__(512,2) acts like CUDA min-BLOCKS -> 4
// waves/SIMD -> 128-VGPR cap -> wf[48] (192 regs) spilled to scratch. v6's
// 7350cy/step decomposed: (a) per-word SERIAL poll retries (each a dependent
// ~250cy L2 round trip), (b) __syncthreads drains vmcnt(0) -> the ~900cy gx
// HBM prefetch forced complete INSIDE every step. v8 fixes:
//   - (512,1): 1 block x 8 waves / 4 EU = 2 waves/SIMD -> 256-VGPR cap, no spill
//   - batched retry: check all 8 words, re-issue ALL in parallel; a retry
//     round = one L2 latency, not N
//   - raw s_barrier + lgkmcnt(0)-only (HK pattern): LDS stage ordering kept,
//     gx loads survive the barrier; pgxA/pgxB double buffer (static idx),
//     issue before stage, consume ~1300cy later
// Shape: 2 groups x 4 WGs x 512 thr (8 waves); wave owns 16 units x 16 batches;
// in-register 3-gate combine via MFMA C layout (col=unit=l15, row=quad*4+r);
// tagged u64 depth-2 ring, relaxed agent atomics (protocol unchanged from the
// twice-passed v6). XCD pinning bid&7 in {0,4}; clr zeroes tags per launch.
__global__ __launch_bounds__(256) void clr_kernel(u64* __restrict__ p) {
  p[(size_t)blockIdx.x * 256 + threadIdx.x] = 0ull;
}

template <typename GxT>
__global__ __launch_bounds__(512, 1) void gru_seq(const GxT* __restrict__ gx,      // [T][32][1536]
                                                  const float* __restrict__ w_hh,  // [1536][512]
                                                  const float* __restrict__ b_ih,
                                                  const float* __restrict__ b_hh,
                                                  u64* __restrict__ h_buf,         // [2 grp][2 slot][16 b][256 w]
                                                  int tb,
                                                  short* __restrict__ x_out,       // [T][32][512] bf16 or null
                                                  float* __restrict__ f_out,       // [32][T][512] fp32 or null
                                                  const int* __restrict__ seq_lens) {
  const int bid = blockIdx.x;                 // grid 32
  const int xs = bid & 7;
  int g;
  if (xs == 0) g = 0;
  else if (xs == 4) g = 1;
  else return;                                // dummy WG (XCD-pinning pad)
  const int wg = bid >> 3;                    // 0..3: unit-block of 128
  const int tid = threadIdx.x;                // 0..511
  const int lane = tid & 63, wave = tid >> 6; // 8 waves
  const int l15 = lane & 15, quad = lane >> 4;
  const int u = wg * 128 + wave * 16 + l15;   // owned unit

  __shared__ u32 h_lds[2][16 * 256];          // 32 KB double-buffered h tile

  u64* hb = h_buf + (size_t)g * 8192;

  // --- persistent w_hh fragments: 3 gates x 16 kb (192 VGPR) ---
  s16x8 wf[48];
#pragma unroll
  for (int kb = 0; kb < 16; ++kb)
#pragma unroll
    for (int gt = 0; gt < 3; ++gt) {
      const float* p = w_hh + (size_t)(gt * 512 + u) * 512 + kb * 32 + quad * 8;
      wf[gt * 16 + kb] = f2bf8(*(const float4*)p, *(const float4*)(p + 4));
    }

  const float bihr = b_ih[u], bihz = b_ih[512 + u], bihn = b_ih[1024 + u];
  const float bhhr = b_hh[u], bhhz = b_hh[512 + u], bhhn = b_hh[1024 + u];

  float hprev[4] = {0.f, 0.f, 0.f, 0.f};
  int slen[4] = {0, 0, 0, 0};
  float pgxA[3][4], pgxB[3][4];
#pragma unroll
  for (int r = 0; r < 4; ++r) {
    const int gb = g * 16 + quad * 4 + r;
    if (f_out) slen[r] = seq_lens[gb];
#pragma unroll
    for (int gt = 0; gt < 3; ++gt) {
      pgxA[gt][r] = ldgx(&gx[(size_t)gb * G3 + gt * 512 + u]);   // t=0
      pgxB[gt][r] = 0.f;
    }
  }

  // poll mapping: thread owns col tid&255, rows rowbase..rowbase+7
  const int colt = tid & 255;
  const int rowbase = (tid >> 8) * 8;

  for (int t = 0; t < TT; ++t) {
    // ---- coalesced poll of h(t-1): batched parallel retry ----
    if (t > 0) {
      const u64* base = hb + ((t - 1) & 1) * 4096 + rowbase * 256 + colt;
      const u32 want = (u32)(tb + t);
      u64 v[8];
#pragma unroll
      for (int j = 0; j < 8; ++j) v[j] = ald(base + j * 256);
      for (;;) {
        u32 bad = 0;
#pragma unroll
        for (int j = 0; j < 8; ++j) bad |= ((u32)(v[j] >> 32)) ^ want;
        if (bad == 0) break;
#pragma unroll
        for (int j = 0; j < 8; ++j) v[j] = ald(base + j * 256);
      }
      // ---- gx prefetch for t+1 issued NOW (survives the raw barrier,
      //      consumed at loop end => ~1 full step of latency cover) ----
      if (t + 1 < TT) {
#pragma unroll
        for (int gt = 0; gt < 3; ++gt)
#pragma unroll
          for (int r = 0; r < 4; ++r) {
            const int gb = g * 16 + quad * 4 + r;
            pgxB[gt][r] = ldgx(&gx[(size_t)((t + 1) * NB + gb) * G3 + gt * 512 + u]);
          }
      }
      // ---- swizzled LDS stage ----
      u32* dl = h_lds[t & 1];
#pragma unroll
      for (int j = 0; j < 8; ++j) {
        const int row = rowbase + j;                        // row&7 == j&7
        dl[row * 256 + (colt ^ ((row & 7) << 2) ^ ((row & 1) << 4))] = (u32)v[j];
      }
    } else {
#pragma unroll
      for (int gt = 0; gt < 3; ++gt)
#pragma unroll
        for (int r = 0; r < 4; ++r) {
          const int gb = g * 16 + quad * 4 + r;
          pgxB[gt][r] = ldgx(&gx[(size_t)((t + 1) * NB + gb) * G3 + gt * 512 + u]);
        }
    }
    // ---- raw barrier: wait only LDS writes, keep gx loads in flight ----
    asm volatile("s_waitcnt lgkmcnt(0)" ::: "memory");
    __builtin_amdgcn_sched_barrier(0);
    __builtin_amdgcn_s_barrier();

    // ---- gate MFMAs from LDS (3 round-robin acc chains) ----
    f32x4 ar = {0.f, 0.f, 0.f, 0.f}, az = ar, an = ar;
    if (t > 0) {
      const u32* hl = h_lds[t & 1];
      const int rbase = l15 * 256;
      const int rx = ((l15 & 7) << 2) ^ ((l15 & 1) << 4);
#pragma unroll
      for (int i = 0; i < 16; ++i) {
        const s16x8 fr = *(const s16x8*)&hl[rbase + ((quad * 4 + i * 16) ^ rx)];
        ar = __builtin_amdgcn_mfma_f32_16x16x32_bf16(fr, wf[i],      ar, 0, 0, 0);
        az = __builtin_amdgcn_mfma_f32_16x16x32_bf16(fr, wf[16 + i], az, 0, 0, 0);
        an = __builtin_amdgcn_mfma_f32_16x16x32_bf16(fr, wf[32 + i], an, 0, 0, 0);
      }
    }

    // ---- in-register combine + tagged h store (earliest visibility) ----
    u64* dst = hb + (t & 1) * 4096;
    const u64 tg = ((u64)(u32)(tb + t + 1)) << 32;
#pragma unroll
    for (int r = 0; r < 4; ++r) {
      const float xr = pgxA[0][r] + bihr + ar[r] + bhhr;
      const float xz = pgxA[1][r] + bihz + az[r] + bhhz;
      const float rr = 1.f / (1.f + __expf(-xr));
      const float zz = 1.f / (1.f + __expf(-xz));
      const float pre = pgxA[2][r] + bihn + rr * (an[r] + bhhn);
      const float ax = fabsf(pre);
      const float e = __expf(-2.f * ax);
      const float nn = copysignf((1.f - e) / (1.f + e), pre);
      const float h = (1.f - zz) * nn + zz * hprev[r];
      hprev[r] = h;
      const float other = __shfl_xor(h, 1);
      if (!(lane & 1))
        __hip_atomic_store(dst + (quad * 4 + r) * 256 + (u >> 1), (u64)pk2(h, other) | tg,
                           __ATOMIC_RELAXED, __HIP_MEMORY_SCOPE_AGENT);
    }
    // ---- output stores (off the critical path) ----
#pragma unroll
    for (int r = 0; r < 4; ++r) {
      const int gb = g * 16 + quad * 4 + r;
      if (x_out) x_out[(size_t)(t * NB + gb) * 512 + u] = f2bf(hprev[r]);
      if (f_out) f_out[((size_t)gb * TT + t) * 512 + u] = (t < slen[r]) ? hprev[r] : 0.f;
    }
    // ---- consume prefetch (gx loads wait HERE, ~1 step after issue) ----
#pragma unroll
    for (int gt = 0; gt < 3; ++gt)
#pragma unroll
      for (int r = 0; r < 4; ++r) pgxA[gt][r] = pgxB[gt][r];
  }
}

extern "C" void kernel_launch(void* const* d_in, const int* in_sizes, int n_in,
                              void* d_out, int out_size, void* d_ws, size_t ws_size,
                              hipStream_t stream) {
  (void)in_sizes; (void)n_in; (void)out_size;
  const float* z       = (const float*)d_in[0];
  const int*   seq     = (const int*)d_in[1];
  const float* chord   = (const float*)d_in[2];
  const float* fc_w    = (const float*)d_in[3];
  const float* fc_b    = (const float*)d_in[4];
  const float* w_ih[3] = {(const float*)d_in[5], (const float*)d_in[9],  (const float*)d_in[13]};
  const float* w_hh[3] = {(const float*)d_in[6], (const float*)d_in[10], (const float*)d_in[14]};
  const float* b_ih[3] = {(const float*)d_in[7], (const float*)d_in[11], (const float*)d_in[15]};
  const float* b_hh[3] = {(const float*)d_in[8], (const float*)d_in[12], (const float*)d_in[16]};

  char* w = (char*)d_ws;
  size_t off = 0;
  auto alloc = [&](size_t bytes) -> void* {
    void* p = w + off;
    off = (off + bytes + 255) & ~(size_t)255;
    return p;
  };
  u64*   hbuf = (u64*)alloc((size_t)2 * 8192 * 8);           // tagged h rings (128 KB)
  float* hfc  = (float*)alloc((size_t)NB * HIDDEN * 4);
  short* x0   = (short*)alloc((size_t)TT * NB * HIDDEN * 2);
  short* x1   = (short*)alloc((size_t)TT * NB * GOUT * 2);   // reused as x2
  short* w0b  = (short*)alloc((size_t)G3 * HIDDEN * 2);
  short* w1b  = (short*)alloc((size_t)G3 * GOUT * 2);
  short* w2b  = (short*)alloc((size_t)G3 * GOUT * 2);
  size_t fixed = off;
  bool gx_f32 = (fixed + (size_t)TT * NB * G3 * 4) <= ws_size;
  void* gx = alloc(gx_f32 ? (size_t)TT * NB * G3 * 4 : (size_t)TT * NB * G3 * 2);

  clr_kernel<<<64, 256, 0, stream>>>(hbuf);
  fc_kernel<<<128, 256, 0, stream>>>(z, fc_w, fc_b, hfc);
  x0_kernel<<<TT * NB, 256, 0, stream>>>(hfc, chord, x0);
  cvt_kernel<<<(G3 * HIDDEN / 4 + 255) / 256, 256, 0, stream>>>(w_ih[0], w0b, G3 * HIDDEN / 4);
  cvt_kernel<<<(G3 * GOUT / 4 + 255) / 256, 256, 0, stream>>>(w_ih[1], w1b, G3 * GOUT / 4);
  cvt_kernel<<<(G3 * GOUT / 4 + 255) / 256, 256, 0, stream>>>(w_ih[2], w2b, G3 * GOUT / 4);

  dim3 gg(G3 / 128, TT * NB / 128);
  if (gx_f32) {
    float* gxf = (float*)gx;
    gemm_bt<float><<<gg, 256, 0, stream>>>(x0, w0b, gxf, TT * NB, G3, HIDDEN);
    gru_seq<float><<<32, 512, 0, stream>>>(gxf, w_hh[0], b_ih[0], b_hh[0], hbuf, 0 * 1024, x1, nullptr, seq);
    gemm_bt<float><<<gg, 256, 0, stream>>>(x1, w1b, gxf, TT * NB, G3, GOUT);
    gru_seq<float><<<32, 512, 0, stream>>>(gxf, w_hh[1], b_ih[1], b_hh[1], hbuf, 1 * 1024, x1, nullptr, seq);
    gemm_bt<float><<<gg, 256, 0, stream>>>(x1, w2b, gxf, TT * NB, G3, GOUT);
    gru_seq<float><<<32, 512, 0, stream>>>(gxf, w_hh[2], b_ih[2], b_hh[2], hbuf, 2 * 1024, nullptr, (float*)d_out, seq);
  } else {
    short* gxb = (short*)gx;
    gemm_bt<short><<<gg, 256, 0, stream>>>(x0, w0b, gxb, TT * NB, G3, HIDDEN);
    gru_seq<short><<<32, 512, 0, stream>>>(gxb, w_hh[0], b_ih[0], b_hh[0], hbuf, 0 * 1024, x1, nullptr, seq);
    gemm_bt<short><<<gg, 256, 0, stream>>>(x1, w1b, gxb, TT * NB, G3, GOUT);
    gru_seq<short><<<32, 512, 0, stream>>>(gxb, w_hh[1], b_ih[1], b_hh[1], hbuf, 1 * 1024, x1, nullptr, seq);
    gemm_bt<short><<<gg, 256, 0, stream>>>(x1, w2b, gxb, TT * NB, G3, GOUT);
    gru_seq<short><<<32, 512, 0, stream>>>(gxb, w_hh[2], b_ih[2], b_hh[2], hbuf, 2 * 1024, nullptr, (float*)d_out, seq);
  }
}

// Round 7
// 5430.278 us; speedup vs baseline: 1.8802x; 1.8491x over previous
//
#include <hip/hip_runtime.h>
#include <hip/hip_bf16.h>
#include <stdint.h>

#define LATENT 256
#define HIDDEN 1024
#define GOUT 512
#define NB 32
#define TT 512
#define G3 1536

typedef float f32x4 __attribute__((ext_vector_type(4)));
typedef short s16x8 __attribute__((ext_vector_type(8)));
typedef uint32_t u32;
typedef unsigned long long u64;

#define GLP(p) ((const __attribute__((address_space(1))) u32*)(p))
#define LLP(p) ((__attribute__((address_space(3))) u32*)(p))

__device__ __forceinline__ short f2bf(float f) {
  u32 u = __builtin_bit_cast(u32, f);
  u32 r = (u + 0x7FFFu + ((u >> 16) & 1u)) >> 16;
  return (short)r;
}
__device__ __forceinline__ float bf2f(short s) {
  u32 u = ((u32)(unsigned short)s) << 16;
  return __builtin_bit_cast(float, u);
}
__device__ __forceinline__ u32 pk2(float a, float b) {
  return (u32)(unsigned short)f2bf(a) | ((u32)(unsigned short)f2bf(b) << 16);
}
__device__ __forceinline__ s16x8 f2bf8(float4 a, float4 b) {
  s16x8 r;
  r[0] = f2bf(a.x); r[1] = f2bf(a.y); r[2] = f2bf(a.z); r[3] = f2bf(a.w);
  r[4] = f2bf(b.x); r[5] = f2bf(b.y); r[6] = f2bf(b.z); r[7] = f2bf(b.w);
  return r;
}
__device__ __forceinline__ float ldgx(const float* p) { return *p; }
__device__ __forceinline__ float ldgx(const short* p) { return bf2f(*p); }
__device__ __forceinline__ u64 ald(const u64* p) {
  return __hip_atomic_load(p, __ATOMIC_RELAXED, __HIP_MEMORY_SCOPE_AGENT);
}

// ---------------- fc + relu ----------------
__global__ __launch_bounds__(256) void fc_kernel(const float* __restrict__ z,
                                                 const float* __restrict__ fc_w,
                                                 const float* __restrict__ fc_b,
                                                 float* __restrict__ hfc) {
  __shared__ float zs[LATENT];
  int tid = threadIdx.x;
  int gid = blockIdx.x * 256 + tid;
  int b = gid >> 10, j = gid & 1023;
  zs[tid] = z[b * LATENT + tid];
  __syncthreads();
  const float4* wr = (const float4*)(fc_w + (size_t)j * LATENT);
  float s = 0.f;
#pragma unroll
  for (int k = 0; k < LATENT / 4; ++k) {
    float4 wv = wr[k];
    float4 zv = *(const float4*)&zs[k * 4];
    s += wv.x * zv.x + wv.y * zv.y + wv.z * zv.z + wv.w * zv.w;
  }
  s += fc_b[j];
  hfc[gid] = fmaxf(s, 0.f);
}

// ------------- x0[t][b][k] = bf16(hfc[b][k] + chord[b][t][k]/100) -------------
__global__ __launch_bounds__(256) void x0_kernel(const float* __restrict__ hfc,
                                                 const float* __restrict__ chord,
                                                 short* __restrict__ x0) {
  int r = blockIdx.x;          // r = t*32 + b
  int b = r & 31, t = r >> 5;
  int k = threadIdx.x * 4;
  float4 c = *(const float4*)(chord + ((size_t)b * TT + t) * HIDDEN + k);
  float4 h = *(const float4*)(hfc + (size_t)b * HIDDEN + k);
  u32 p0 = pk2(h.x + c.x * 0.01f, h.y + c.y * 0.01f);
  u32 p1 = pk2(h.z + c.z * 0.01f, h.w + c.w * 0.01f);
  uint2 pv; pv.x = p0; pv.y = p1;
  *(uint2*)(x0 + (size_t)r * HIDDEN + k) = pv;
}

// ---------------- fp32 -> bf16 weight convert ----------------
__global__ __launch_bounds__(256) void cvt_kernel(const float* __restrict__ src,
                                                  short* __restrict__ dst, int n4) {
  int i = blockIdx.x * 256 + threadIdx.x;
  if (i < n4) {
    float4 v = ((const float4*)src)[i];
    uint2 pv; pv.x = pk2(v.x, v.y); pv.y = pk2(v.z, v.w);
    ((uint2*)dst)[i] = pv;
  }
}

// ---------------- GEMM: C[M][N] = A[M][K](bf16) @ Bw[N][K]^T(bf16) ----------------
template <typename OutT>
__global__ __launch_bounds__(256) void gemm_bt(const short* __restrict__ A,
                                               const short* __restrict__ Bw,
                                               OutT* __restrict__ C, int M, int N, int K) {
  __shared__ short As[128 * 32];
  __shared__ short Bs[128 * 32];
  const int tid = threadIdx.x;
  const int lane = tid & 63, wave = tid >> 6;
  const int l15 = lane & 15, quad = lane >> 4;
  const int n0 = blockIdx.x * 128, m0 = blockIdx.y * 128;
  const int wm = (wave >> 1) * 64, wn = (wave & 1) * 64;
  f32x4 acc[4][4] = {};
  for (int k0 = 0; k0 < K; k0 += 32) {
#pragma unroll
    for (int c = 0; c < 2; ++c) {
      int idx = c * 256 + tid;
      int row = idx >> 2, cs = (idx & 3) * 8;
      const u32* ga = (const u32*)(A + (size_t)(m0 + row) * K + k0 + cs);
      const u32* gb = (const u32*)(Bw + (size_t)(n0 + row) * K + k0 + cs);
      u32* sa = (u32*)As + (size_t)(c * 256 + wave * 64) * 4;
      u32* sb = (u32*)Bs + (size_t)(c * 256 + wave * 64) * 4;
      __builtin_amdgcn_global_load_lds(GLP(ga), LLP(sa), 16, 0, 0);
      __builtin_amdgcn_global_load_lds(GLP(gb), LLP(sb), 16, 0, 0);
    }
    __syncthreads();
    s16x8 af[4], bfr[4];
#pragma unroll
    for (int i = 0; i < 4; ++i)
      af[i] = *(const s16x8*)(As + (wm + i * 16 + l15) * 32 + quad * 8);
#pragma unroll
    for (int j = 0; j < 4; ++j)
      bfr[j] = *(const s16x8*)(Bs + (wn + j * 16 + l15) * 32 + quad * 8);
#pragma unroll
    for (int i = 0; i < 4; ++i)
#pragma unroll
      for (int j = 0; j < 4; ++j)
        acc[i][j] = __builtin_amdgcn_mfma_f32_16x16x32_bf16(af[i], bfr[j], acc[i][j], 0, 0, 0);
    __syncthreads();
  }
#pragma unroll
  for (int i = 0; i < 4; ++i)
#pragma unroll
    for (int j = 0; j < 4; ++j)
#pragma unroll
      for (int r = 0; r < 4; ++r) {
        int m = m0 + wm + i * 16 + quad * 4 + r;
        int n = n0 + wn + j * 16 + l15;
        float v = acc[i][j][r];
        if constexpr (__is_same(OutT, float)) C[(size_t)m * N + n] = v;
        else C[(size_t)m * N + n] = f2bf(v);
      }
}

// ================= GRU layer v9: v6 shape + v8 scheduling fixes ==============
// Post-mortem v7/v8: 512-thread blocks got a 128-VGPR cap from hipcc under
// BOTH __launch_bounds__(512,2) and (512,1) -> wf[48] (192 regs) spilled ->
// ~2.2x slower than v6, masking v8's (correct) scheduling fixes. v6's shape
// (256 thr, __launch_bounds__(256,1)) measured VGPR_Count=256, no spill.
// v9 = v6 shape + v8 fixes:
//   - batched parallel retry: check all 16 poll words, re-issue ALL on a miss;
//     one retry round = one L2 latency (v6: serial per-word dependent rounds)
//   - raw s_barrier + lgkmcnt(0)-only wait: LDS-stage ordering preserved, but
//     in-flight gx loads survive the barrier (v6: __syncthreads drained
//     vmcnt(0), forcing the ~900cy gx HBM prefetch into every step)
//   - pgxA/pgxB double buffer (static indices): gx issued AFTER poll consume
//     (so polls never wait on gx via in-order vmcnt retirement), consumed at
//     loop end (~full step of latency cover)
// Shape: 2 groups x 16 batches; 8 WGs/group x 256 thr (4 waves, 1/SIMD).
// Wave owns 16 units x 16 batches; in-register 3-gate combine via MFMA C
// layout (col=unit=l15, row=batch=quad*4+r); tagged u64 depth-2 ring, relaxed
// agent atomics (protocol of the twice-passed v6/v8); per-layer tag_base;
// clr zeroes tags per launch; XCD pinning bid&7 in {0,4}.
__global__ __launch_bounds__(256) void clr_kernel(u64* __restrict__ p) {
  p[(size_t)blockIdx.x * 256 + threadIdx.x] = 0ull;
}

template <typename GxT>
__global__ __launch_bounds__(256, 1) void gru_seq(const GxT* __restrict__ gx,      // [T][32][1536]
                                                  const float* __restrict__ w_hh,  // [1536][512]
                                                  const float* __restrict__ b_ih,
                                                  const float* __restrict__ b_hh,
                                                  u64* __restrict__ h_buf,         // [2 grp][2 slot][16 b][256 w]
                                                  int tb,
                                                  short* __restrict__ x_out,       // [T][32][512] bf16 or null
                                                  float* __restrict__ f_out,       // [32][T][512] fp32 or null
                                                  const int* __restrict__ seq_lens) {
  const int bid = blockIdx.x;                 // grid 64
  const int xs = bid & 7;
  int g;
  if (xs == 0) g = 0;
  else if (xs == 4) g = 1;
  else return;                                // dummy WG (XCD-pinning pad)
  const int wg = bid >> 3;                    // 0..7: unit-block of 64
  const int tid = threadIdx.x;                // 0..255
  const int lane = tid & 63, wave = tid >> 6; // 4 waves
  const int l15 = lane & 15, quad = lane >> 4;
  const int u = wg * 64 + wave * 16 + l15;    // owned unit

  __shared__ u32 h_lds[2][16 * 256];          // 32 KB double-buffered h tile

  u64* hb = h_buf + (size_t)g * 8192;

  // --- persistent w_hh fragments: 3 gates x 16 kb (192 VGPR) ---
  s16x8 wf[48];
#pragma unroll
  for (int kb = 0; kb < 16; ++kb)
#pragma unroll
    for (int gt = 0; gt < 3; ++gt) {
      const float* p = w_hh + (size_t)(gt * 512 + u) * 512 + kb * 32 + quad * 8;
      wf[gt * 16 + kb] = f2bf8(*(const float4*)p, *(const float4*)(p + 4));
    }

  const float bihr = b_ih[u], bihz = b_ih[512 + u], bihn = b_ih[1024 + u];
  const float bhhr = b_hh[u], bhhz = b_hh[512 + u], bhhn = b_hh[1024 + u];

  float hprev[4] = {0.f, 0.f, 0.f, 0.f};
  int slen[4] = {0, 0, 0, 0};
  float pgxA[3][4], pgxB[3][4];
#pragma unroll
  for (int r = 0; r < 4; ++r) {
    const int gb = g * 16 + quad * 4 + r;
    if (f_out) slen[r] = seq_lens[gb];
#pragma unroll
    for (int gt = 0; gt < 3; ++gt) {
      pgxA[gt][r] = ldgx(&gx[(size_t)gb * G3 + gt * 512 + u]);   // t=0
      pgxB[gt][r] = 0.f;
    }
  }

  for (int t = 0; t < TT; ++t) {
    // ---- coalesced poll of h(t-1): batched parallel retry ----
    if (t > 0) {
      const u64* src = hb + ((t - 1) & 1) * 4096 + tid;
      const u32 want = (u32)(tb + t);
      u64 v[16];
#pragma unroll
      for (int j = 0; j < 16; ++j) v[j] = ald(src + j * 256);
      for (;;) {
        u32 bad = 0;
#pragma unroll
        for (int j = 0; j < 16; ++j) bad |= ((u32)(v[j] >> 32)) ^ want;
        if (bad == 0) break;
#pragma unroll
        for (int j = 0; j < 16; ++j) v[j] = ald(src + j * 256);
      }
      // ---- gx prefetch for t+1: issued AFTER poll consume (polls never wait
      //      on gx), survives the raw barrier, consumed at loop end ----
      if (t + 1 < TT) {
#pragma unroll
        for (int gt = 0; gt < 3; ++gt)
#pragma unroll
          for (int r = 0; r < 4; ++r) {
            const int gb = g * 16 + quad * 4 + r;
            pgxB[gt][r] = ldgx(&gx[(size_t)((t + 1) * NB + gb) * G3 + gt * 512 + u]);
          }
      }
      // ---- swizzled LDS stage ----
      u32* dl = h_lds[t & 1];
#pragma unroll
      for (int j = 0; j < 16; ++j)
        dl[j * 256 + (tid ^ ((j & 7) << 2) ^ ((j & 1) << 4))] = (u32)v[j];
    } else {
#pragma unroll
      for (int gt = 0; gt < 3; ++gt)
#pragma unroll
        for (int r = 0; r < 4; ++r) {
          const int gb = g * 16 + quad * 4 + r;
          pgxB[gt][r] = ldgx(&gx[(size_t)((t + 1) * NB + gb) * G3 + gt * 512 + u]);
        }
    }
    // ---- raw barrier: wait only LDS writes, keep gx loads in flight ----
    asm volatile("s_waitcnt lgkmcnt(0)" ::: "memory");
    __builtin_amdgcn_sched_barrier(0);
    __builtin_amdgcn_s_barrier();

    // ---- gate MFMAs from LDS (3 round-robin acc chains) ----
    f32x4 ar = {0.f, 0.f, 0.f, 0.f}, az = ar, an = ar;
    if (t > 0) {
      const u32* hl = h_lds[t & 1];
      const int rbase = l15 * 256;
      const int rx = ((l15 & 7) << 2) ^ ((l15 & 1) << 4);
#pragma unroll
      for (int i = 0; i < 16; ++i) {
        const s16x8 fr = *(const s16x8*)&hl[rbase + ((quad * 4 + i * 16) ^ rx)];
        ar = __builtin_amdgcn_mfma_f32_16x16x32_bf16(fr, wf[i],      ar, 0, 0, 0);
        az = __builtin_amdgcn_mfma_f32_16x16x32_bf16(fr, wf[16 + i], az, 0, 0, 0);
        an = __builtin_amdgcn_mfma_f32_16x16x32_bf16(fr, wf[32 + i], an, 0, 0, 0);
      }
    }

    // ---- in-register combine + tagged h store (earliest visibility) ----
    u64* dst = hb + (t & 1) * 4096;
    const u64 tg = ((u64)(u32)(tb + t + 1)) << 32;
#pragma unroll
    for (int r = 0; r < 4; ++r) {
      const float xr = pgxA[0][r] + bihr + ar[r] + bhhr;
      const float xz = pgxA[1][r] + bihz + az[r] + bhhz;
      const float rr = 1.f / (1.f + __expf(-xr));
      const float zz = 1.f / (1.f + __expf(-xz));
      const float pre = pgxA[2][r] + bihn + rr * (an[r] + bhhn);
      const float ax = fabsf(pre);
      const float e = __expf(-2.f * ax);
      const float nn = copysignf((1.f - e) / (1.f + e), pre);
      const float h = (1.f - zz) * nn + zz * hprev[r];
      hprev[r] = h;
      const float other = __shfl_xor(h, 1);
      if (!(lane & 1))
        __hip_atomic_store(dst + (quad * 4 + r) * 256 + (u >> 1), (u64)pk2(h, other) | tg,
                           __ATOMIC_RELAXED, __HIP_MEMORY_SCOPE_AGENT);
    }
    // ---- output stores (off the critical path) ----
#pragma unroll
    for (int r = 0; r < 4; ++r) {
      const int gb = g * 16 + quad * 4 + r;
      if (x_out) x_out[(size_t)(t * NB + gb) * 512 + u] = f2bf(hprev[r]);
      if (f_out) f_out[((size_t)gb * TT + t) * 512 + u] = (t < slen[r]) ? hprev[r] : 0.f;
    }
    // ---- consume prefetch (gx loads wait HERE, ~1 full step after issue) ----
#pragma unroll
    for (int gt = 0; gt < 3; ++gt)
#pragma unroll
      for (int r = 0; r < 4; ++r) pgxA[gt][r] = pgxB[gt][r];
  }
}

extern "C" void kernel_launch(void* const* d_in, const int* in_sizes, int n_in,
                              void* d_out, int out_size, void* d_ws, size_t ws_size,
                              hipStream_t stream) {
  (void)in_sizes; (void)n_in; (void)out_size;
  const float* z       = (const float*)d_in[0];
  const int*   seq     = (const int*)d_in[1];
  const float* chord   = (const float*)d_in[2];
  const float* fc_w    = (const float*)d_in[3];
  const float* fc_b    = (const float*)d_in[4];
  const float* w_ih[3] = {(const float*)d_in[5], (const float*)d_in[9],  (const float*)d_in[13]};
  const float* w_hh[3] = {(const float*)d_in[6], (const float*)d_in[10], (const float*)d_in[14]};
  const float* b_ih[3] = {(const float*)d_in[7], (const float*)d_in[11], (const float*)d_in[15]};
  const float* b_hh[3] = {(const float*)d_in[8], (const float*)d_in[12], (const float*)d_in[16]};

  char* w = (char*)d_ws;
  size_t off = 0;
  auto alloc = [&](size_t bytes) -> void* {
    void* p = w + off;
    off = (off + bytes + 255) & ~(size_t)255;
    return p;
  };
  u64*   hbuf = (u64*)alloc((size_t)2 * 8192 * 8);           // tagged h rings (128 KB)
  float* hfc  = (float*)alloc((size_t)NB * HIDDEN * 4);
  short* x0   = (short*)alloc((size_t)TT * NB * HIDDEN * 2);
  short* x1   = (short*)alloc((size_t)TT * NB * GOUT * 2);   // reused as x2
  short* w0b  = (short*)alloc((size_t)G3 * HIDDEN * 2);
  short* w1b  = (short*)alloc((size_t)G3 * GOUT * 2);
  short* w2b  = (short*)alloc((size_t)G3 * GOUT * 2);
  size_t fixed = off;
  bool gx_f32 = (fixed + (size_t)TT * NB * G3 * 4) <= ws_size;
  void* gx = alloc(gx_f32 ? (size_t)TT * NB * G3 * 4 : (size_t)TT * NB * G3 * 2);

  clr_kernel<<<64, 256, 0, stream>>>(hbuf);
  fc_kernel<<<128, 256, 0, stream>>>(z, fc_w, fc_b, hfc);
  x0_kernel<<<TT * NB, 256, 0, stream>>>(hfc, chord, x0);
  cvt_kernel<<<(G3 * HIDDEN / 4 + 255) / 256, 256, 0, stream>>>(w_ih[0], w0b, G3 * HIDDEN / 4);
  cvt_kernel<<<(G3 * GOUT / 4 + 255) / 256, 256, 0, stream>>>(w_ih[1], w1b, G3 * GOUT / 4);
  cvt_kernel<<<(G3 * GOUT / 4 + 255) / 256, 256, 0, stream>>>(w_ih[2], w2b, G3 * GOUT / 4);

  dim3 gg(G3 / 128, TT * NB / 128);
  if (gx_f32) {
    float* gxf = (float*)gx;
    gemm_bt<float><<<gg, 256, 0, stream>>>(x0, w0b, gxf, TT * NB, G3, HIDDEN);
    gru_seq<float><<<64, 256, 0, stream>>>(gxf, w_hh[0], b_ih[0], b_hh[0], hbuf, 0 * 1024, x1, nullptr, seq);
    gemm_bt<float><<<gg, 256, 0, stream>>>(x1, w1b, gxf, TT * NB, G3, GOUT);
    gru_seq<float><<<64, 256, 0, stream>>>(gxf, w_hh[1], b_ih[1], b_hh[1], hbuf, 1 * 1024, x1, nullptr, seq);
    gemm_bt<float><<<gg, 256, 0, stream>>>(x1, w2b, gxf, TT * NB, G3, GOUT);
    gru_seq<float><<<64, 256, 0, stream>>>(gxf, w_hh[2], b_ih[2], b_hh[2], hbuf, 2 * 1024, nullptr, (float*)d_out, seq);
  } else {
    short* gxb = (short*)gx;
    gemm_bt<short><<<gg, 256, 0, stream>>>(x0, w0b, gxb, TT * NB, G3, HIDDEN);
    gru_seq<short><<<64, 256, 0, stream>>>(gxb, w_hh[0], b_ih[0], b_hh[0], hbuf, 0 * 1024, x1, nullptr, seq);
    gemm_bt<short><<<gg, 256, 0, stream>>>(x1, w1b, gxb, TT * NB, G3, GOUT);
    gru_seq<short><<<64, 256, 0, stream>>>(gxb, w_hh[1], b_ih[1], b_hh[1], hbuf, 1 * 1024, x1, nullptr, seq);
    gemm_bt<short><<<gg, 256, 0, stream>>>(x1, w2b, gxb, TT * NB, G3, GOUT);
    gru_seq<short><<<64, 256, 0, stream>>>(gxb, w_hh[2], b_ih[2], b_hh[2], hbuf, 2 * 1024, nullptr, (float*)d_out, seq);
  }
}